// Round 17
// baseline (340.589 us; speedup 1.0000x reference)
//
#include <hip/hip_runtime.h>

#define N_NODES 50000
#define N_EDGES 600000
#define N_GRAPHS 500
#define F 128

typedef short bf16x8 __attribute__((ext_vector_type(8)));
typedef float f32x4 __attribute__((ext_vector_type(4)));
union U4H8 { uint4 u; bf16x8 h; };

// ---- bf16 helpers (RNE) ----
__device__ inline unsigned pk_bf16(float a, float b) {
    unsigned ua = __float_as_uint(a), ub = __float_as_uint(b);
    ua = (ua + 0x7fffu + ((ua >> 16) & 1u)) >> 16;
    ub = (ub + 0x7fffu + ((ub >> 16) & 1u)) >> 16;
    return ua | (ub << 16);
}
__device__ inline float bf16_rnd(float x) {
    unsigned u = __float_as_uint(x);
    u = (u + 0x7fffu + ((u >> 16) & 1u)) & 0xffff0000u;
    return __uint_as_float(u);
}
__device__ inline unsigned short bf16_1(float a) {
    unsigned ua = __float_as_uint(a);
    return (unsigned short)((ua + 0x7fffu + ((ua >> 16) & 1u)) >> 16);
}
#define BF_LO(u) __uint_as_float((u) << 16)
#define BF_HI(u) __uint_as_float((u) & 0xffff0000u)

#define G_CVT  3125
#define G_HIST 2344
#define G_PREPW 24

// ================= merged prep: x->bf16 | dst histogram | W split-pack =================
__global__ __launch_bounds__(256) void k_prep(const float* __restrict__ x, unsigned short* __restrict__ xb,
                                              const int* __restrict__ dst, int* __restrict__ cnt,
                                              const float* __restrict__ W1, const float* __restrict__ W2,
                                              const float* __restrict__ W3,
                                              uint4* __restrict__ Whi, uint4* __restrict__ Wlo) {
    int b = blockIdx.x, tid = threadIdx.x;
    if (b < G_CVT) {
        int idx = b * 256 + tid;
        if (idx < N_NODES * F / 8) {
            const float4* xr = (const float4*)(x + (size_t)idx * 8);
            float4 a = xr[0], c = xr[1];
            uint4 o;
            o.x = pk_bf16(a.x, a.y); o.y = pk_bf16(a.z, a.w);
            o.z = pk_bf16(c.x, c.y); o.w = pk_bf16(c.z, c.w);
            ((uint4*)xb)[idx] = o;
        }
    } else if (b < G_CVT + G_HIST) {
        int e = (b - G_CVT) * 256 + tid;
        if (e < N_EDGES) atomicAdd(&cnt[dst[e]], 1);
    } else {
        int idx = (b - G_CVT - G_HIST) * 256 + tid;   // 0..6143
        int layer = idx >> 11;
        const float* W = (layer == 0) ? W1 : (layer == 1) ? W2 : W3;
        int t = idx & 2047;
        int lane = t & 63, sc = t >> 6;
        int s = sc >> 3, c = sc & 7;
        int q = lane >> 4, m = lane & 15;
        int k0 = 32 * s + 8 * q, n0 = 16 * c + m;
        float w[8], h[8];
        #pragma unroll
        for (int j = 0; j < 8; ++j) {
            w[j] = W[(k0 + j) * F + n0];
            h[j] = bf16_rnd(w[j]);
        }
        uint4 uh, ul;
        uh.x = pk_bf16(h[0], h[1]); uh.y = pk_bf16(h[2], h[3]);
        uh.z = pk_bf16(h[4], h[5]); uh.w = pk_bf16(h[6], h[7]);
        ul.x = pk_bf16(w[0] - h[0], w[1] - h[1]); ul.y = pk_bf16(w[2] - h[2], w[3] - h[3]);
        ul.z = pk_bf16(w[4] - h[4], w[5] - h[5]); ul.w = pk_bf16(w[6] - h[6], w[7] - h[7]);
        Whi[idx] = uh;
        Wlo[idx] = ul;
    }
}

// ================= CSR scan + fill =================
__global__ __launch_bounds__(256) void k_scan1(const int* __restrict__ cnt, int* __restrict__ row_ptr,
                                               int* __restrict__ blksums, float* __restrict__ dinv, int n) {
    __shared__ int s[256];
    int i = blockIdx.x * 256 + threadIdx.x;
    int v = (i < n) ? cnt[i] : 0;
    if (i < n) dinv[i] = rsqrtf((float)(v + 1));
    s[threadIdx.x] = v;
    __syncthreads();
    for (int off = 1; off < 256; off <<= 1) {
        int t = (threadIdx.x >= off) ? s[threadIdx.x - off] : 0;
        __syncthreads();
        s[threadIdx.x] += t;
        __syncthreads();
    }
    if (i < n) row_ptr[i] = s[threadIdx.x] - v;
    if (threadIdx.x == 255) blksums[blockIdx.x] = s[255];
}

__global__ __launch_bounds__(256) void k_scan23(int* __restrict__ row_ptr, const int* __restrict__ blksums,
                                                int n, int ne) {
    __shared__ int s[256];
    int tid = threadIdx.x;
    s[tid] = (tid < (int)blockIdx.x) ? blksums[tid] : 0;
    __syncthreads();
    for (int off = 128; off > 0; off >>= 1) {
        if (tid < off) s[tid] += s[tid + off];
        __syncthreads();
    }
    int base = s[0];
    int i = blockIdx.x * 256 + tid;
    if (i < n) row_ptr[i] += base;
    if (i == 0) row_ptr[n] = ne;
}

__global__ __launch_bounds__(256) void k_fill(const int* __restrict__ src, const int* __restrict__ dst,
                                              const int* __restrict__ row_ptr, int* __restrict__ cnt,
                                              const float* __restrict__ dinv,
                                              int2* __restrict__ esw, int ne) {
    int e = blockIdx.x * 256 + threadIdx.x;
    if (e < ne) {
        int d = dst[e];
        int s = src[e];
        int pos = row_ptr[d] + atomicSub(&cnt[d], 1) - 1;
        esw[pos] = make_int2(s, __float_as_int(dinv[s]));
    }
}

// ============ fused aggregate-first layer: Hout = bf16(relu(Agg(Hin) @ W + b)) ============
// TN=16 nodes/block; ONE WAVE PER NODE-GROUP: wave handles 4 nodes sequentially; per edge
// the wave issues one async global_load_lds (64 lanes x 4B = the whole 256B bf16 row) into
// a 16-slot per-wave LDS ring -> 16 rows in flight with no VGPR data pressure.
// Consume: 1 ds_read_b32/lane + 2 FMA per edge. Self-loop = virtual edge at `end`.
// Phase 2: A-frags from bf16 Gb via ds_read_b128; W hi/lo streamed (2 MFMAs/tile).
#define TN 16
#define GP2 136    // bf16 row stride (shorts)
#define CAPE 768
__global__ __launch_bounds__(256) void k_fused(const int* __restrict__ row_ptr,
                                               const int2* __restrict__ esw,
                                               const float* __restrict__ dinv,
                                               const unsigned short* __restrict__ Hin,
                                               const uint4* __restrict__ Whi,
                                               const uint4* __restrict__ Wlo,
                                               const float* __restrict__ bias,
                                               unsigned short* __restrict__ Hout, int n) {
    __shared__ unsigned short Gb[TN * GP2];          // 4.25 KB
    __shared__ uint2 eL[CAPE];                       // 6 KB
    __shared__ unsigned short rowbuf[4][16][128];    // 16 KB: per-wave 16-slot row ring
    __shared__ int rp[TN + 1];
    __shared__ float ddl[TN];
    int tid = threadIdx.x;
    int wave = tid >> 6, lane = tid & 63;
    int d0 = blockIdx.x * TN;

    // ---- phase 0: stage rp, dinv, edge records ----
    int dTN = d0 + TN; if (dTN > n) dTN = n;
    int e0 = row_ptr[d0];
    int e1 = row_ptr[dTN];
    if (tid <= TN) {
        int d = d0 + tid; if (d > n) d = n;
        rp[tid] = row_ptr[d];
    }
    if (tid < TN) {
        int d = d0 + tid;
        ddl[tid] = (d < n) ? dinv[d] : 0.f;
    }
    int nE = e1 - e0; if (nE > CAPE) nE = CAPE;
    for (int i = tid; i < nE; i += 256) eL[i] = ((const uint2*)esw)[e0 + i];
    __syncthreads();

    // ---- phase 1: wave handles nodes wave*4 .. wave*4+3 ----
    for (int k = 0; k < 4; ++k) {
        int nl = wave * 4 + k;
        int node = d0 + nl;
        float a0 = 0.f, a1 = 0.f;
        if (node < n) {
            int beg = rp[nl], end = rp[nl + 1];    // edges [beg,end), self at e==end
            float dd = ddl[nl];
            for (int c = beg; c <= end; c += 16) {
                int ns = end - c + 1; if (ns > 16) ns = 16;
                // row indices (wave-uniform reads)
                int rows[16];
                #pragma unroll
                for (int j = 0; j < 16; ++j) {
                    if (j < ns) {
                        int e = c + j;
                        if (e == end) rows[j] = node;
                        else {
                            int off = e - e0;
                            rows[j] = (off < CAPE) ? (int)eL[off].x
                                                   : (int)((const uint2*)esw)[e].x;
                        }
                    }
                }
                // issue async row loads: lane loads 4B at gptr+4*lane -> rowbuf slot
                #pragma unroll
                for (int j = 0; j < 16; ++j) {
                    if (j < ns) {
                        const unsigned* gp = (const unsigned*)(Hin + (size_t)rows[j] * F) + lane;
                        __builtin_amdgcn_global_load_lds(
                            (const __attribute__((address_space(1))) unsigned*)gp,
                            (__attribute__((address_space(3))) unsigned*)&rowbuf[wave][j][0],
                            4, 0, 0);
                    }
                }
                __builtin_amdgcn_s_waitcnt(0);   // drain async loads before LDS consume
                // consume
                #pragma unroll
                for (int j = 0; j < 16; ++j) {
                    if (j < ns) {
                        int e = c + j;
                        float w;
                        if (e == end) w = dd * dd;
                        else {
                            int off = e - e0;
                            unsigned wy = (off < CAPE) ? eL[off].y
                                                       : (unsigned)((const uint2*)esw)[e].y;
                            w = __uint_as_float(wy) * dd;
                        }
                        unsigned v = *(const unsigned*)&rowbuf[wave][j][lane * 2];
                        a0 = fmaf(BF_LO(v), w, a0);
                        a1 = fmaf(BF_HI(v), w, a1);
                    }
                }
            }
        }
        *(unsigned*)&Gb[nl * GP2 + lane * 2] = (node < n) ? pk_bf16(a0, a1) : 0u;
    }
    __syncthreads();

    // ---- phase 2: MFMA. 16 rows; wave handles col tiles 2*wave, 2*wave+1 ----
    int q = lane >> 4, m = lane & 15;
    f32x4 acc[2];
    acc[0] = (f32x4){0.f, 0.f, 0.f, 0.f};
    acc[1] = (f32x4){0.f, 0.f, 0.f, 0.f};
    #pragma unroll
    for (int s = 0; s < 4; ++s) {
        U4H8 a;
        a.u = *(const uint4*)&Gb[m * GP2 + 32 * s + 8 * q];
        #pragma unroll
        for (int cc = 0; cc < 2; ++cc) {
            int c = wave * 2 + cc;
            U4H8 bh, bl;
            bh.u = Whi[(s * 8 + c) * 64 + lane];
            bl.u = Wlo[(s * 8 + c) * 64 + lane];
            acc[cc] = __builtin_amdgcn_mfma_f32_16x16x32_bf16(a.h, bh.h, acc[cc], 0, 0, 0);
            acc[cc] = __builtin_amdgcn_mfma_f32_16x16x32_bf16(a.h, bl.h, acc[cc], 0, 0, 0);
        }
    }
    __syncthreads();

    // ---- epilogue: bias + relu -> Gb (transpose), coalesced bf16 store ----
    #pragma unroll
    for (int cc = 0; cc < 2; ++cc) {
        int c = wave * 2 + cc;
        float bb = bias[16 * c + m];
        #pragma unroll
        for (int r = 0; r < 4; ++r)
            Gb[(4 * q + r) * GP2 + 16 * c + m] = bf16_1(fmaxf(acc[cc][r] + bb, 0.f));
    }
    __syncthreads();
    {
        int row = tid >> 4, c8 = tid & 15;   // 256 threads = 16 rows x 16 uint4
        int node = d0 + row;
        if (node < n) {
            uint4 o = *(const uint4*)&Gb[row * GP2 + c8 * 8];
            ((uint4*)(Hout + (size_t)node * F))[c8] = o;
        }
    }
}

// ============ fused pool (segment mean, bf16 in) + FC head ============
__global__ __launch_bounds__(256) void k_pool_fc(const unsigned short* __restrict__ Hb,
                                                 const int* __restrict__ batch,
                                                 const float* __restrict__ Wf1,
                                                 const float* __restrict__ bf1,
                                                 const float* __restrict__ Wf2,
                                                 const float* __restrict__ bf2,
                                                 float* __restrict__ out) {
    int g = blockIdx.x;
    int tid = threadIdx.x;
    int lo = 0, hi = N_NODES;
    while (lo < hi) { int mid = (lo + hi) >> 1; if (batch[mid] < g) lo = mid + 1; else hi = mid; }
    int start = lo;
    hi = N_NODES;
    while (lo < hi) { int mid = (lo + hi) >> 1; if (batch[mid] <= g) lo = mid + 1; else hi = mid; }
    int end = lo;

    __shared__ float hs[4][F];
    __shared__ float hg[F];
    int wv = tid >> 6, lane = tid & 63;
    int half = lane >> 5, sub = lane & 31;
    float4 a = make_float4(0.f, 0.f, 0.f, 0.f);
    for (int i = start + wv * 2 + half; i < end; i += 8) {
        uint2 v = ((const uint2*)(Hb + (size_t)i * F))[sub];
        a.x += BF_LO(v.x); a.y += BF_HI(v.x);
        a.z += BF_LO(v.y); a.w += BF_HI(v.y);
    }
    a.x += __shfl_xor(a.x, 32, 64);
    a.y += __shfl_xor(a.y, 32, 64);
    a.z += __shfl_xor(a.z, 32, 64);
    a.w += __shfl_xor(a.w, 32, 64);
    if (half == 0) ((float4*)hs[wv])[sub] = a;
    __syncthreads();
    if (tid < F) {
        float inv = 1.0f / (float)((end - start) > 0 ? (end - start) : 1);
        hg[tid] = (hs[0][tid] + hs[1][tid] + hs[2][tid] + hs[3][tid]) * inv;
    }
    __syncthreads();
    if (tid < 64) {
        float acc = bf1[tid];
        #pragma unroll 4
        for (int f = 0; f < F; ++f) acc = fmaf(hg[f], Wf1[f * 64 + tid], acc);
        float v = fmaxf(acc, 0.f) * Wf2[tid];
        #pragma unroll
        for (int off = 32; off > 0; off >>= 1) v += __shfl_down(v, off, 64);
        if (tid == 0) out[g] = v + bf2[0];
    }
}

extern "C" void kernel_launch(void* const* d_in, const int* in_sizes, int n_in,
                              void* d_out, int out_size, void* d_ws, size_t ws_size,
                              hipStream_t stream) {
    const float* x    = (const float*)d_in[0];
    const int* eidx   = (const int*)d_in[1];
    const int* batch  = (const int*)d_in[2];
    const float* W1   = (const float*)d_in[3];
    const float* b1   = (const float*)d_in[4];
    const float* W2   = (const float*)d_in[5];
    const float* b2   = (const float*)d_in[6];
    const float* W3   = (const float*)d_in[7];
    const float* b3   = (const float*)d_in[8];
    const float* Wf1  = (const float*)d_in[9];
    const float* bf1  = (const float*)d_in[10];
    const float* Wf2  = (const float*)d_in[11];
    const float* bf2  = (const float*)d_in[12];
    float* out = (float*)d_out;

    const int* src = eidx;
    const int* dst = eidx + N_EDGES;

    char* p = (char*)d_ws;
    unsigned short* Xb  = (unsigned short*)p;  p += (size_t)N_NODES * F * 2;
    unsigned short* H1  = (unsigned short*)p;  p += (size_t)N_NODES * F * 2;
    unsigned short* H2  = (unsigned short*)p;  p += (size_t)N_NODES * F * 2;
    unsigned short* H3  = (unsigned short*)p;  p += (size_t)N_NODES * F * 2;
    int2* esw   = (int2*)p;    p += (size_t)N_EDGES * sizeof(int2);
    uint4* Whi  = (uint4*)p;   p += (size_t)3 * 2048 * sizeof(uint4);
    uint4* Wlo  = (uint4*)p;   p += (size_t)3 * 2048 * sizeof(uint4);
    float* dinv = (float*)p;   p += (size_t)N_NODES * sizeof(float);
    int* cnt     = (int*)p;    p += (size_t)N_NODES * sizeof(int);
    int* row_ptr = (int*)p;    p += (size_t)(N_NODES + 1) * sizeof(int);
    int* blksums = (int*)p;    p += 256 * sizeof(int);

    dim3 b256(256);
    int gNodes = (N_NODES + 255) / 256;           // 196
    int gEdges = (N_EDGES + 255) / 256;
    int gFused = (N_NODES + TN - 1) / TN;         // 3125

    // ---- prep (cvt + hist + prepW merged); cnt must be zero before hist ----
    hipMemsetAsync(cnt, 0, (size_t)N_NODES * sizeof(int), stream);
    k_prep<<<G_CVT + G_HIST + G_PREPW, b256, 0, stream>>>(x, Xb, dst, cnt, W1, W2, W3, Whi, Wlo);

    // ---- CSR scan + fill ----
    k_scan1<<<gNodes, b256, 0, stream>>>(cnt, row_ptr, blksums, dinv, N_NODES);
    k_scan23<<<gNodes, b256, 0, stream>>>(row_ptr, blksums, N_NODES, N_EDGES);
    k_fill<<<gEdges, b256, 0, stream>>>(src, dst, row_ptr, cnt, dinv, esw, N_EDGES);

    // ---- 3 aggregate-first fused layers ----
    k_fused<<<gFused, b256, 0, stream>>>(row_ptr, esw, dinv, Xb, Whi,        Wlo,        b1, H1, N_NODES);
    k_fused<<<gFused, b256, 0, stream>>>(row_ptr, esw, dinv, H1, Whi + 2048, Wlo + 2048, b2, H2, N_NODES);
    k_fused<<<gFused, b256, 0, stream>>>(row_ptr, esw, dinv, H2, Whi + 4096, Wlo + 4096, b3, H3, N_NODES);

    // ---- pool + FC ----
    k_pool_fc<<<N_GRAPHS, b256, 0, stream>>>(H3, batch, Wf1, bf1, Wf2, bf2, out);
}

// Round 18
// 268.104 us; speedup vs baseline: 1.2704x; 1.2704x over previous
//
#include <hip/hip_runtime.h>

#define N_NODES 50000
#define N_EDGES 600000
#define N_GRAPHS 500
#define F 128

typedef short bf16x8 __attribute__((ext_vector_type(8)));
typedef float f32x4 __attribute__((ext_vector_type(4)));
union U4H8 { uint4 u; bf16x8 h; };

// ---- bf16 helpers (RNE) ----
__device__ inline unsigned pk_bf16(float a, float b) {
    unsigned ua = __float_as_uint(a), ub = __float_as_uint(b);
    ua = (ua + 0x7fffu + ((ua >> 16) & 1u)) >> 16;
    ub = (ub + 0x7fffu + ((ub >> 16) & 1u)) >> 16;
    return ua | (ub << 16);
}
__device__ inline float bf16_rnd(float x) {
    unsigned u = __float_as_uint(x);
    u = (u + 0x7fffu + ((u >> 16) & 1u)) & 0xffff0000u;
    return __uint_as_float(u);
}
__device__ inline unsigned short bf16_1(float a) {
    unsigned ua = __float_as_uint(a);
    return (unsigned short)((ua + 0x7fffu + ((ua >> 16) & 1u)) >> 16);
}
#define BF_LO(u) __uint_as_float((u) << 16)
#define BF_HI(u) __uint_as_float((u) & 0xffff0000u)

#define G_CVT  3125
#define G_HIST 2344
#define G_PREPW 24
#define G_BND  196

// ====== merged prep: x->bf16 | dst histogram | W split-pack | pool segment bounds ======
__global__ __launch_bounds__(256) void k_prep(const float* __restrict__ x, unsigned short* __restrict__ xb,
                                              const int* __restrict__ dst, int* __restrict__ cnt,
                                              const float* __restrict__ W1, const float* __restrict__ W2,
                                              const float* __restrict__ W3,
                                              uint4* __restrict__ Whi, uint4* __restrict__ Wlo,
                                              const int* __restrict__ batch, int* __restrict__ gs) {
    int b = blockIdx.x, tid = threadIdx.x;
    if (b < G_CVT) {
        int idx = b * 256 + tid;
        if (idx < N_NODES * F / 8) {
            const float4* xr = (const float4*)(x + (size_t)idx * 8);
            float4 a = xr[0], c = xr[1];
            uint4 o;
            o.x = pk_bf16(a.x, a.y); o.y = pk_bf16(a.z, a.w);
            o.z = pk_bf16(c.x, c.y); o.w = pk_bf16(c.z, c.w);
            ((uint4*)xb)[idx] = o;
        }
    } else if (b < G_CVT + G_HIST) {
        int e = (b - G_CVT) * 256 + tid;
        if (e < N_EDGES) atomicAdd(&cnt[dst[e]], 1);
    } else if (b < G_CVT + G_HIST + G_PREPW) {
        int idx = (b - G_CVT - G_HIST) * 256 + tid;   // 0..6143
        int layer = idx >> 11;
        const float* W = (layer == 0) ? W1 : (layer == 1) ? W2 : W3;
        int t = idx & 2047;
        int lane = t & 63, sc = t >> 6;
        int s = sc >> 3, c = sc & 7;
        int q = lane >> 4, m = lane & 15;
        int k0 = 32 * s + 8 * q, n0 = 16 * c + m;
        float w[8], h[8];
        #pragma unroll
        for (int j = 0; j < 8; ++j) {
            w[j] = W[(k0 + j) * F + n0];
            h[j] = bf16_rnd(w[j]);
        }
        uint4 uh, ul;
        uh.x = pk_bf16(h[0], h[1]); uh.y = pk_bf16(h[2], h[3]);
        uh.z = pk_bf16(h[4], h[5]); uh.w = pk_bf16(h[6], h[7]);
        ul.x = pk_bf16(w[0] - h[0], w[1] - h[1]); ul.y = pk_bf16(w[2] - h[2], w[3] - h[3]);
        ul.z = pk_bf16(w[4] - h[4], w[5] - h[5]); ul.w = pk_bf16(w[6] - h[6], w[7] - h[7]);
        Whi[idx] = uh;
        Wlo[idx] = ul;
    } else {
        // pool segment bounds: batch sorted; gs[g] = first node index with batch >= g
        int i = (b - G_CVT - G_HIST - G_PREPW) * 256 + tid;
        if (i < N_NODES) {
            int bi = batch[i];
            if (i == 0) {
                for (int g = 0; g <= bi; ++g) gs[g] = 0;
            } else {
                int bp = batch[i - 1];
                for (int g = bp + 1; g <= bi; ++g) gs[g] = i;
            }
            if (i == N_NODES - 1) {
                for (int g = bi + 1; g <= N_GRAPHS; ++g) gs[g] = N_NODES;
            }
        }
    }
}

// ================= CSR scan + fill =================
__global__ __launch_bounds__(256) void k_scan1(const int* __restrict__ cnt, int* __restrict__ row_ptr,
                                               int* __restrict__ blksums, float* __restrict__ dinv, int n) {
    __shared__ int s[256];
    int i = blockIdx.x * 256 + threadIdx.x;
    int v = (i < n) ? cnt[i] : 0;
    if (i < n) dinv[i] = rsqrtf((float)(v + 1));
    s[threadIdx.x] = v;
    __syncthreads();
    for (int off = 1; off < 256; off <<= 1) {
        int t = (threadIdx.x >= off) ? s[threadIdx.x - off] : 0;
        __syncthreads();
        s[threadIdx.x] += t;
        __syncthreads();
    }
    if (i < n) row_ptr[i] = s[threadIdx.x] - v;
    if (threadIdx.x == 255) blksums[blockIdx.x] = s[255];
}

__global__ __launch_bounds__(256) void k_scan23(int* __restrict__ row_ptr, const int* __restrict__ blksums,
                                                int n, int ne) {
    __shared__ int s[256];
    int tid = threadIdx.x;
    s[tid] = (tid < (int)blockIdx.x) ? blksums[tid] : 0;
    __syncthreads();
    for (int off = 128; off > 0; off >>= 1) {
        if (tid < off) s[tid] += s[tid + off];
        __syncthreads();
    }
    int base = s[0];
    int i = blockIdx.x * 256 + tid;
    if (i < n) row_ptr[i] += base;
    if (i == 0) row_ptr[n] = ne;
}

__global__ __launch_bounds__(256) void k_fill(const int* __restrict__ src, const int* __restrict__ dst,
                                              const int* __restrict__ row_ptr, int* __restrict__ cnt,
                                              const float* __restrict__ dinv,
                                              int2* __restrict__ esw, int ne) {
    int e = blockIdx.x * 256 + threadIdx.x;
    if (e < ne) {
        int d = dst[e];
        int s = src[e];
        int pos = row_ptr[d] + atomicSub(&cnt[d], 1) - 1;
        esw[pos] = make_int2(s, __float_as_int(dinv[s]));
    }
}

// ============ fused aggregate-first layer: Hout = bf16(relu(Agg(Hin) @ W + b)) ============
// 32-node tile, LDS 17.2 KB, NO min-waves bound (r11/r15/r17 lessons).
// Phase 0: stage tile's CSR edges in LDS. Phase 1: 16 groups x 16 lanes gather (8-deep
// batched loads, LDS broadcast edge reads) -> bf16 G (A-frag layout).
// Phase 2: A = ds_read_b128 of G; 2 MFMAs per tile (A-bf16 x W hi/lo). Epilogue via G.
#define TN 32
#define GP2 136
#define MAXE_L 1024
__global__ __launch_bounds__(256) void k_fused(const int* __restrict__ row_ptr,
                                               const int2* __restrict__ esw,
                                               const float* __restrict__ dinv,
                                               const unsigned short* __restrict__ Hin,
                                               const uint4* __restrict__ Whi,
                                               const uint4* __restrict__ Wlo,
                                               const float* __restrict__ bias,
                                               unsigned short* __restrict__ Hout, int n) {
    __shared__ unsigned short Gb[TN * GP2];   // 8.7 KB
    __shared__ uint2 eL[MAXE_L];              // 8 KB
    __shared__ int rp[TN + 1];
    __shared__ float ddl[TN];
    int tid = threadIdx.x;
    int d0 = blockIdx.x * TN;

    // ---- phase 0 ----
    int dTN = d0 + TN; if (dTN > n) dTN = n;
    int e0 = row_ptr[d0];
    int e1 = row_ptr[dTN];
    if (tid <= TN) {
        int d = d0 + tid; if (d > n) d = n;
        rp[tid] = row_ptr[d];
    }
    if (tid < TN) {
        int d = d0 + tid;
        ddl[tid] = (d < n) ? dinv[d] : 0.f;
    }
    int nE = e1 - e0; if (nE > MAXE_L) nE = MAXE_L;
    for (int i = tid; i < nE; i += 256) eL[i] = ((const uint2*)esw)[e0 + i];
    __syncthreads();

    int grp = tid >> 4, sub = tid & 15;

    // ---- phase 1: gather; group handles local nodes 2*grp, 2*grp+1 ----
    #pragma unroll
    for (int i = 0; i < 2; ++i) {
        int nl = 2 * grp + i;
        int node = d0 + nl;
        float4 accL = make_float4(0.f, 0.f, 0.f, 0.f);
        float4 accH = make_float4(0.f, 0.f, 0.f, 0.f);
        if (node < n) {
            int beg = rp[nl], end = rp[nl + 1];
            float dd = ddl[nl];
            // self-loop first
            uint4 srow = ((const uint4*)(Hin + (size_t)node * F))[sub];
            float ws = dd * dd;
            accL.x = BF_LO(srow.x) * ws;
            accL.y = BF_HI(srow.x) * ws;
            accL.z = BF_LO(srow.y) * ws;
            accL.w = BF_HI(srow.y) * ws;
            accH.x = BF_LO(srow.z) * ws;
            accH.y = BF_HI(srow.z) * ws;
            accH.z = BF_LO(srow.w) * ws;
            accH.w = BF_HI(srow.w) * ws;
            for (int c = beg; c < end; c += 8) {
                int sjs[8];
                #pragma unroll
                for (int j = 0; j < 8; ++j) {
                    int e = c + j;
                    int sj = node;
                    if (e < end) {
                        int off = e - e0;
                        sj = (off < MAXE_L) ? (int)((const unsigned*)eL)[2 * off]
                                            : ((const uint2*)esw)[e].x;
                    }
                    sjs[j] = sj;
                }
                uint4 rows[8];
                #pragma unroll
                for (int j = 0; j < 8; ++j)
                    rows[j] = ((const uint4*)(Hin + (size_t)sjs[j] * F))[sub];
                #pragma unroll
                for (int j = 0; j < 8; ++j) {
                    int e = c + j;
                    float wj = 0.f;
                    if (e < end) {
                        int off = e - e0;
                        unsigned wb = (off < MAXE_L) ? ((const unsigned*)eL)[2 * off + 1]
                                                     : (unsigned)((const uint2*)esw)[e].y;
                        wj = __uint_as_float(wb) * dd;
                    }
                    accL.x = fmaf(BF_LO(rows[j].x), wj, accL.x);
                    accL.y = fmaf(BF_HI(rows[j].x), wj, accL.y);
                    accL.z = fmaf(BF_LO(rows[j].y), wj, accL.z);
                    accL.w = fmaf(BF_HI(rows[j].y), wj, accL.w);
                    accH.x = fmaf(BF_LO(rows[j].z), wj, accH.x);
                    accH.y = fmaf(BF_HI(rows[j].z), wj, accH.y);
                    accH.z = fmaf(BF_LO(rows[j].w), wj, accH.z);
                    accH.w = fmaf(BF_HI(rows[j].w), wj, accH.w);
                }
            }
        }
        uint4 o;
        o.x = pk_bf16(accL.x, accL.y);
        o.y = pk_bf16(accL.z, accL.w);
        o.z = pk_bf16(accH.x, accH.y);
        o.w = pk_bf16(accH.z, accH.w);
        *(uint4*)&Gb[nl * GP2 + 8 * sub] = o;
    }
    __syncthreads();

    // ---- phase 2: MFMA (A bf16 from LDS, W hi/lo from L2: 2 MFMAs per tile) ----
    int wave = tid >> 6, lane = tid & 63;
    int q = lane >> 4, m = lane & 15;
    int rt = wave & 1;
    int ch = (wave >> 1) * 4;
    int row0 = 16 * rt;
    f32x4 acc[4];
    #pragma unroll
    for (int c = 0; c < 4; ++c) acc[c] = (f32x4){0.f, 0.f, 0.f, 0.f};
    #pragma unroll
    for (int s = 0; s < 4; ++s) {
        U4H8 a;
        a.u = *(const uint4*)&Gb[(row0 + m) * GP2 + 32 * s + 8 * q];
        #pragma unroll
        for (int cc = 0; cc < 4; ++cc) {
            int c = ch + cc;
            U4H8 bh, bl;
            bh.u = Whi[(s * 8 + c) * 64 + lane];
            bl.u = Wlo[(s * 8 + c) * 64 + lane];
            acc[cc] = __builtin_amdgcn_mfma_f32_16x16x32_bf16(a.h, bh.h, acc[cc], 0, 0, 0);
            acc[cc] = __builtin_amdgcn_mfma_f32_16x16x32_bf16(a.h, bl.h, acc[cc], 0, 0, 0);
        }
    }
    __syncthreads();

    // ---- epilogue: bias + relu -> Gb (transpose), coalesced bf16 store ----
    #pragma unroll
    for (int cc = 0; cc < 4; ++cc) {
        int c = ch + cc;
        float bb = bias[16 * c + m];
        #pragma unroll
        for (int r = 0; r < 4; ++r)
            Gb[(row0 + 4 * q + r) * GP2 + 16 * c + m] = bf16_1(fmaxf(acc[cc][r] + bb, 0.f));
    }
    __syncthreads();
    #pragma unroll
    for (int j = 0; j < 2; ++j) {
        int lin = tid + 256 * j;
        int row = lin >> 4, c8 = lin & 15;
        int node = d0 + row;
        if (node < n) {
            uint4 o = *(const uint4*)&Gb[row * GP2 + c8 * 8];
            ((uint4*)(Hout + (size_t)node * F))[c8] = o;
        }
    }
}

// ============ fused pool (segment mean via precomputed bounds) + FC head ============
__global__ __launch_bounds__(256) void k_pool_fc(const unsigned short* __restrict__ Hb,
                                                 const int* __restrict__ gs,
                                                 const float* __restrict__ Wf1,
                                                 const float* __restrict__ bf1,
                                                 const float* __restrict__ Wf2,
                                                 const float* __restrict__ bf2,
                                                 float* __restrict__ out) {
    int g = blockIdx.x;
    int tid = threadIdx.x;
    int start = gs[g], end = gs[g + 1];

    __shared__ float hs[4][F];
    __shared__ float hg[F];
    int wv = tid >> 6, lane = tid & 63;
    int half = lane >> 5, sub = lane & 31;
    float4 a = make_float4(0.f, 0.f, 0.f, 0.f);
    for (int i = start + wv * 2 + half; i < end; i += 8) {
        uint2 v = ((const uint2*)(Hb + (size_t)i * F))[sub];
        a.x += BF_LO(v.x); a.y += BF_HI(v.x);
        a.z += BF_LO(v.y); a.w += BF_HI(v.y);
    }
    a.x += __shfl_xor(a.x, 32, 64);
    a.y += __shfl_xor(a.y, 32, 64);
    a.z += __shfl_xor(a.z, 32, 64);
    a.w += __shfl_xor(a.w, 32, 64);
    if (half == 0) ((float4*)hs[wv])[sub] = a;
    __syncthreads();
    if (tid < F) {
        float inv = 1.0f / (float)((end - start) > 0 ? (end - start) : 1);
        hg[tid] = (hs[0][tid] + hs[1][tid] + hs[2][tid] + hs[3][tid]) * inv;
    }
    __syncthreads();
    if (tid < 64) {
        float acc = bf1[tid];
        #pragma unroll 4
        for (int f = 0; f < F; ++f) acc = fmaf(hg[f], Wf1[f * 64 + tid], acc);
        float v = fmaxf(acc, 0.f) * Wf2[tid];
        #pragma unroll
        for (int off = 32; off > 0; off >>= 1) v += __shfl_down(v, off, 64);
        if (tid == 0) out[g] = v + bf2[0];
    }
}

extern "C" void kernel_launch(void* const* d_in, const int* in_sizes, int n_in,
                              void* d_out, int out_size, void* d_ws, size_t ws_size,
                              hipStream_t stream) {
    const float* x    = (const float*)d_in[0];
    const int* eidx   = (const int*)d_in[1];
    const int* batch  = (const int*)d_in[2];
    const float* W1   = (const float*)d_in[3];
    const float* b1   = (const float*)d_in[4];
    const float* W2   = (const float*)d_in[5];
    const float* b2   = (const float*)d_in[6];
    const float* W3   = (const float*)d_in[7];
    const float* b3   = (const float*)d_in[8];
    const float* Wf1  = (const float*)d_in[9];
    const float* bf1  = (const float*)d_in[10];
    const float* Wf2  = (const float*)d_in[11];
    const float* bf2  = (const float*)d_in[12];
    float* out = (float*)d_out;

    const int* src = eidx;
    const int* dst = eidx + N_EDGES;

    char* p = (char*)d_ws;
    unsigned short* Xb  = (unsigned short*)p;  p += (size_t)N_NODES * F * 2;
    unsigned short* H1  = (unsigned short*)p;  p += (size_t)N_NODES * F * 2;
    unsigned short* H2  = (unsigned short*)p;  p += (size_t)N_NODES * F * 2;
    unsigned short* H3  = (unsigned short*)p;  p += (size_t)N_NODES * F * 2;
    int2* esw   = (int2*)p;    p += (size_t)N_EDGES * sizeof(int2);
    uint4* Whi  = (uint4*)p;   p += (size_t)3 * 2048 * sizeof(uint4);
    uint4* Wlo  = (uint4*)p;   p += (size_t)3 * 2048 * sizeof(uint4);
    float* dinv = (float*)p;   p += (size_t)N_NODES * sizeof(float);
    int* cnt     = (int*)p;    p += (size_t)N_NODES * sizeof(int);
    int* row_ptr = (int*)p;    p += (size_t)(N_NODES + 1) * sizeof(int);
    int* blksums = (int*)p;    p += 256 * sizeof(int);
    int* gs      = (int*)p;    p += (size_t)(N_GRAPHS + 1) * sizeof(int);

    dim3 b256(256);
    int gNodes = (N_NODES + 255) / 256;           // 196
    int gEdges = (N_EDGES + 255) / 256;
    int gFused = (N_NODES + TN - 1) / TN;         // 1563

    // ---- prep (cvt + hist + prepW + pool bounds merged); cnt must be zero before hist ----
    hipMemsetAsync(cnt, 0, (size_t)N_NODES * sizeof(int), stream);
    k_prep<<<G_CVT + G_HIST + G_PREPW + G_BND, b256, 0, stream>>>(x, Xb, dst, cnt, W1, W2, W3,
                                                                  Whi, Wlo, batch, gs);

    // ---- CSR scan + fill ----
    k_scan1<<<gNodes, b256, 0, stream>>>(cnt, row_ptr, blksums, dinv, N_NODES);
    k_scan23<<<gNodes, b256, 0, stream>>>(row_ptr, blksums, N_NODES, N_EDGES);
    k_fill<<<gEdges, b256, 0, stream>>>(src, dst, row_ptr, cnt, dinv, esw, N_EDGES);

    // ---- 3 aggregate-first fused layers ----
    k_fused<<<gFused, b256, 0, stream>>>(row_ptr, esw, dinv, Xb, Whi,        Wlo,        b1, H1, N_NODES);
    k_fused<<<gFused, b256, 0, stream>>>(row_ptr, esw, dinv, H1, Whi + 2048, Wlo + 2048, b2, H2, N_NODES);
    k_fused<<<gFused, b256, 0, stream>>>(row_ptr, esw, dinv, H2, Whi + 4096, Wlo + 4096, b3, H3, N_NODES);

    // ---- pool + FC ----
    k_pool_fc<<<N_GRAPHS, b256, 0, stream>>>(H3, gs, Wf1, bf1, Wf2, bf2, out);
}

// Round 19
// 267.991 us; speedup vs baseline: 1.2709x; 1.0004x over previous
//
#include <hip/hip_runtime.h>

#define N_NODES 50000
#define N_EDGES 600000
#define N_GRAPHS 500
#define F 128

typedef short bf16x8 __attribute__((ext_vector_type(8)));
typedef float f32x4 __attribute__((ext_vector_type(4)));
union U4H8 { uint4 u; bf16x8 h; };

// ---- bf16 helpers (RNE) ----
__device__ inline unsigned pk_bf16(float a, float b) {
    unsigned ua = __float_as_uint(a), ub = __float_as_uint(b);
    ua = (ua + 0x7fffu + ((ua >> 16) & 1u)) >> 16;
    ub = (ub + 0x7fffu + ((ub >> 16) & 1u)) >> 16;
    return ua | (ub << 16);
}
__device__ inline float bf16_rnd(float x) {
    unsigned u = __float_as_uint(x);
    u = (u + 0x7fffu + ((u >> 16) & 1u)) & 0xffff0000u;
    return __uint_as_float(u);
}
__device__ inline unsigned short bf16_1(float a) {
    unsigned ua = __float_as_uint(a);
    return (unsigned short)((ua + 0x7fffu + ((ua >> 16) & 1u)) >> 16);
}
#define BF_LO(u) __uint_as_float((u) << 16)
#define BF_HI(u) __uint_as_float((u) & 0xffff0000u)

#define G_CVT  3125
#define G_HIST 2344
#define G_PREPW 24
#define G_BND  196

// ====== merged prep: x->bf16 | dst histogram | W split-pack | pool segment bounds ======
__global__ __launch_bounds__(256) void k_prep(const float* __restrict__ x, unsigned short* __restrict__ xb,
                                              const int* __restrict__ dst, int* __restrict__ cnt,
                                              const float* __restrict__ W1, const float* __restrict__ W2,
                                              const float* __restrict__ W3,
                                              uint4* __restrict__ Whi, uint4* __restrict__ Wlo,
                                              const int* __restrict__ batch, int* __restrict__ gs) {
    int b = blockIdx.x, tid = threadIdx.x;
    if (b < G_CVT) {
        int idx = b * 256 + tid;
        if (idx < N_NODES * F / 8) {
            const float4* xr = (const float4*)(x + (size_t)idx * 8);
            float4 a = xr[0], c = xr[1];
            uint4 o;
            o.x = pk_bf16(a.x, a.y); o.y = pk_bf16(a.z, a.w);
            o.z = pk_bf16(c.x, c.y); o.w = pk_bf16(c.z, c.w);
            ((uint4*)xb)[idx] = o;
        }
    } else if (b < G_CVT + G_HIST) {
        int e = (b - G_CVT) * 256 + tid;
        if (e < N_EDGES) atomicAdd(&cnt[dst[e]], 1);
    } else if (b < G_CVT + G_HIST + G_PREPW) {
        int idx = (b - G_CVT - G_HIST) * 256 + tid;   // 0..6143
        int layer = idx >> 11;
        const float* W = (layer == 0) ? W1 : (layer == 1) ? W2 : W3;
        int t = idx & 2047;
        int lane = t & 63, sc = t >> 6;
        int s = sc >> 3, c = sc & 7;
        int q = lane >> 4, m = lane & 15;
        int k0 = 32 * s + 8 * q, n0 = 16 * c + m;
        float w[8], h[8];
        #pragma unroll
        for (int j = 0; j < 8; ++j) {
            w[j] = W[(k0 + j) * F + n0];
            h[j] = bf16_rnd(w[j]);
        }
        uint4 uh, ul;
        uh.x = pk_bf16(h[0], h[1]); uh.y = pk_bf16(h[2], h[3]);
        uh.z = pk_bf16(h[4], h[5]); uh.w = pk_bf16(h[6], h[7]);
        ul.x = pk_bf16(w[0] - h[0], w[1] - h[1]); ul.y = pk_bf16(w[2] - h[2], w[3] - h[3]);
        ul.z = pk_bf16(w[4] - h[4], w[5] - h[5]); ul.w = pk_bf16(w[6] - h[6], w[7] - h[7]);
        Whi[idx] = uh;
        Wlo[idx] = ul;
    } else {
        int i = (b - G_CVT - G_HIST - G_PREPW) * 256 + tid;
        if (i < N_NODES) {
            int bi = batch[i];
            if (i == 0) {
                for (int g = 0; g <= bi; ++g) gs[g] = 0;
            } else {
                int bp = batch[i - 1];
                for (int g = bp + 1; g <= bi; ++g) gs[g] = i;
            }
            if (i == N_NODES - 1) {
                for (int g = bi + 1; g <= N_GRAPHS; ++g) gs[g] = N_NODES;
            }
        }
    }
}

// ================= CSR scan + fill =================
__global__ __launch_bounds__(256) void k_scan1(const int* __restrict__ cnt, int* __restrict__ row_ptr,
                                               int* __restrict__ blksums, float* __restrict__ dinv, int n) {
    __shared__ int s[256];
    int i = blockIdx.x * 256 + threadIdx.x;
    int v = (i < n) ? cnt[i] : 0;
    if (i < n) dinv[i] = rsqrtf((float)(v + 1));
    s[threadIdx.x] = v;
    __syncthreads();
    for (int off = 1; off < 256; off <<= 1) {
        int t = (threadIdx.x >= off) ? s[threadIdx.x - off] : 0;
        __syncthreads();
        s[threadIdx.x] += t;
        __syncthreads();
    }
    if (i < n) row_ptr[i] = s[threadIdx.x] - v;
    if (threadIdx.x == 255) blksums[blockIdx.x] = s[255];
}

__global__ __launch_bounds__(256) void k_scan23(int* __restrict__ row_ptr, const int* __restrict__ blksums,
                                                int n, int ne) {
    __shared__ int s[256];
    int tid = threadIdx.x;
    s[tid] = (tid < (int)blockIdx.x) ? blksums[tid] : 0;
    __syncthreads();
    for (int off = 128; off > 0; off >>= 1) {
        if (tid < off) s[tid] += s[tid + off];
        __syncthreads();
    }
    int base = s[0];
    int i = blockIdx.x * 256 + tid;
    if (i < n) row_ptr[i] += base;
    if (i == 0) row_ptr[n] = ne;
}

__global__ __launch_bounds__(256) void k_fill(const int* __restrict__ src, const int* __restrict__ dst,
                                              const int* __restrict__ row_ptr, int* __restrict__ cnt,
                                              const float* __restrict__ dinv,
                                              int2* __restrict__ esw, int ne) {
    int e = blockIdx.x * 256 + threadIdx.x;
    if (e < ne) {
        int d = dst[e];
        int s = src[e];
        int pos = row_ptr[d] + atomicSub(&cnt[d], 1) - 1;
        esw[pos] = make_int2(s, __float_as_int(dinv[s]));
    }
}

// ============ fused aggregate-first layer: Hout = bf16(relu(Agg(Hin) @ W + b)) ============
// TN=16 nodes/block, ONE node per 16-lane group (halves serial latency windows vs 2/group
// and improves barrier balance). LDS ~8.6 KB; NO min-waves bound (r11/r15/r17 lessons).
// Phase 0: stage tile's CSR edges in LDS. Phase 1: 8-deep batched row loads, LDS broadcast
// edge reads -> bf16 G (A-frag layout). Phase 2: ds_read_b128 A-frags; 2 MFMAs/tile.
#define TN 16
#define GP2 136
#define MAXE_L 512
__global__ __launch_bounds__(256) void k_fused(const int* __restrict__ row_ptr,
                                               const int2* __restrict__ esw,
                                               const float* __restrict__ dinv,
                                               const unsigned short* __restrict__ Hin,
                                               const uint4* __restrict__ Whi,
                                               const uint4* __restrict__ Wlo,
                                               const float* __restrict__ bias,
                                               unsigned short* __restrict__ Hout, int n) {
    __shared__ unsigned short Gb[TN * GP2];   // 4.25 KB
    __shared__ uint2 eL[MAXE_L];              // 4 KB
    __shared__ int rp[TN + 1];
    __shared__ float ddl[TN];
    int tid = threadIdx.x;
    int d0 = blockIdx.x * TN;

    // ---- phase 0 ----
    int dTN = d0 + TN; if (dTN > n) dTN = n;
    int e0 = row_ptr[d0];
    int e1 = row_ptr[dTN];
    if (tid <= TN) {
        int d = d0 + tid; if (d > n) d = n;
        rp[tid] = row_ptr[d];
    }
    if (tid < TN) {
        int d = d0 + tid;
        ddl[tid] = (d < n) ? dinv[d] : 0.f;
    }
    int nE = e1 - e0; if (nE > MAXE_L) nE = MAXE_L;
    for (int i = tid; i < nE; i += 256) eL[i] = ((const uint2*)esw)[e0 + i];
    __syncthreads();

    int grp = tid >> 4, sub = tid & 15;

    // ---- phase 1: gather; group handles local node `grp` ----
    {
        int nl = grp;
        int node = d0 + nl;
        float4 accL = make_float4(0.f, 0.f, 0.f, 0.f);
        float4 accH = make_float4(0.f, 0.f, 0.f, 0.f);
        if (node < n) {
            int beg = rp[nl], end = rp[nl + 1];
            float dd = ddl[nl];
            // self-loop first
            uint4 srow = ((const uint4*)(Hin + (size_t)node * F))[sub];
            float ws = dd * dd;
            accL.x = BF_LO(srow.x) * ws;
            accL.y = BF_HI(srow.x) * ws;
            accL.z = BF_LO(srow.y) * ws;
            accL.w = BF_HI(srow.y) * ws;
            accH.x = BF_LO(srow.z) * ws;
            accH.y = BF_HI(srow.z) * ws;
            accH.z = BF_LO(srow.w) * ws;
            accH.w = BF_HI(srow.w) * ws;
            for (int c = beg; c < end; c += 8) {
                int sjs[8];
                #pragma unroll
                for (int j = 0; j < 8; ++j) {
                    int e = c + j;
                    int sj = node;
                    if (e < end) {
                        int off = e - e0;
                        sj = (off < MAXE_L) ? (int)((const unsigned*)eL)[2 * off]
                                            : ((const uint2*)esw)[e].x;
                    }
                    sjs[j] = sj;
                }
                uint4 rows[8];
                #pragma unroll
                for (int j = 0; j < 8; ++j)
                    rows[j] = ((const uint4*)(Hin + (size_t)sjs[j] * F))[sub];
                #pragma unroll
                for (int j = 0; j < 8; ++j) {
                    int e = c + j;
                    float wj = 0.f;
                    if (e < end) {
                        int off = e - e0;
                        unsigned wb = (off < MAXE_L) ? ((const unsigned*)eL)[2 * off + 1]
                                                     : (unsigned)((const uint2*)esw)[e].y;
                        wj = __uint_as_float(wb) * dd;
                    }
                    accL.x = fmaf(BF_LO(rows[j].x), wj, accL.x);
                    accL.y = fmaf(BF_HI(rows[j].x), wj, accL.y);
                    accL.z = fmaf(BF_LO(rows[j].y), wj, accL.z);
                    accL.w = fmaf(BF_HI(rows[j].y), wj, accL.w);
                    accH.x = fmaf(BF_LO(rows[j].z), wj, accH.x);
                    accH.y = fmaf(BF_HI(rows[j].z), wj, accH.y);
                    accH.z = fmaf(BF_LO(rows[j].w), wj, accH.z);
                    accH.w = fmaf(BF_HI(rows[j].w), wj, accH.w);
                }
            }
        }
        uint4 o;
        o.x = pk_bf16(accL.x, accL.y);
        o.y = pk_bf16(accL.z, accL.w);
        o.z = pk_bf16(accH.x, accH.y);
        o.w = pk_bf16(accH.z, accH.w);
        *(uint4*)&Gb[nl * GP2 + 8 * sub] = o;
    }
    __syncthreads();

    // ---- phase 2: MFMA. 16 rows; wave handles col tiles 2*wave, 2*wave+1 ----
    int wave = tid >> 6, lane = tid & 63;
    int q = lane >> 4, m = lane & 15;
    f32x4 acc[2];
    acc[0] = (f32x4){0.f, 0.f, 0.f, 0.f};
    acc[1] = (f32x4){0.f, 0.f, 0.f, 0.f};
    #pragma unroll
    for (int s = 0; s < 4; ++s) {
        U4H8 a;
        a.u = *(const uint4*)&Gb[m * GP2 + 32 * s + 8 * q];
        #pragma unroll
        for (int cc = 0; cc < 2; ++cc) {
            int c = wave * 2 + cc;
            U4H8 bh, bl;
            bh.u = Whi[(s * 8 + c) * 64 + lane];
            bl.u = Wlo[(s * 8 + c) * 64 + lane];
            acc[cc] = __builtin_amdgcn_mfma_f32_16x16x32_bf16(a.h, bh.h, acc[cc], 0, 0, 0);
            acc[cc] = __builtin_amdgcn_mfma_f32_16x16x32_bf16(a.h, bl.h, acc[cc], 0, 0, 0);
        }
    }
    __syncthreads();

    // ---- epilogue: bias + relu -> Gb (transpose), coalesced bf16 store ----
    #pragma unroll
    for (int cc = 0; cc < 2; ++cc) {
        int c = wave * 2 + cc;
        float bb = bias[16 * c + m];
        #pragma unroll
        for (int r = 0; r < 4; ++r)
            Gb[(4 * q + r) * GP2 + 16 * c + m] = bf16_1(fmaxf(acc[cc][r] + bb, 0.f));
    }
    __syncthreads();
    {
        int row = tid >> 4, c8 = tid & 15;   // 256 threads = 16 rows x 16 uint4
        int node = d0 + row;
        if (node < n) {
            uint4 o = *(const uint4*)&Gb[row * GP2 + c8 * 8];
            ((uint4*)(Hout + (size_t)node * F))[c8] = o;
        }
    }
}

// ============ fused pool (segment mean via precomputed bounds) + FC head ============
__global__ __launch_bounds__(256) void k_pool_fc(const unsigned short* __restrict__ Hb,
                                                 const int* __restrict__ gs,
                                                 const float* __restrict__ Wf1,
                                                 const float* __restrict__ bf1,
                                                 const float* __restrict__ Wf2,
                                                 const float* __restrict__ bf2,
                                                 float* __restrict__ out) {
    int g = blockIdx.x;
    int tid = threadIdx.x;
    int start = gs[g], end = gs[g + 1];

    __shared__ float hs[4][F];
    __shared__ float hg[F];
    int wv = tid >> 6, lane = tid & 63;
    int half = lane >> 5, sub = lane & 31;
    float4 a = make_float4(0.f, 0.f, 0.f, 0.f);
    for (int i = start + wv * 2 + half; i < end; i += 8) {
        uint2 v = ((const uint2*)(Hb + (size_t)i * F))[sub];
        a.x += BF_LO(v.x); a.y += BF_HI(v.x);
        a.z += BF_LO(v.y); a.w += BF_HI(v.y);
    }
    a.x += __shfl_xor(a.x, 32, 64);
    a.y += __shfl_xor(a.y, 32, 64);
    a.z += __shfl_xor(a.z, 32, 64);
    a.w += __shfl_xor(a.w, 32, 64);
    if (half == 0) ((float4*)hs[wv])[sub] = a;
    __syncthreads();
    if (tid < F) {
        float inv = 1.0f / (float)((end - start) > 0 ? (end - start) : 1);
        hg[tid] = (hs[0][tid] + hs[1][tid] + hs[2][tid] + hs[3][tid]) * inv;
    }
    __syncthreads();
    if (tid < 64) {
        float acc = bf1[tid];
        #pragma unroll 4
        for (int f = 0; f < F; ++f) acc = fmaf(hg[f], Wf1[f * 64 + tid], acc);
        float v = fmaxf(acc, 0.f) * Wf2[tid];
        #pragma unroll
        for (int off = 32; off > 0; off >>= 1) v += __shfl_down(v, off, 64);
        if (tid == 0) out[g] = v + bf2[0];
    }
}

extern "C" void kernel_launch(void* const* d_in, const int* in_sizes, int n_in,
                              void* d_out, int out_size, void* d_ws, size_t ws_size,
                              hipStream_t stream) {
    const float* x    = (const float*)d_in[0];
    const int* eidx   = (const int*)d_in[1];
    const int* batch  = (const int*)d_in[2];
    const float* W1   = (const float*)d_in[3];
    const float* b1   = (const float*)d_in[4];
    const float* W2   = (const float*)d_in[5];
    const float* b2   = (const float*)d_in[6];
    const float* W3   = (const float*)d_in[7];
    const float* b3   = (const float*)d_in[8];
    const float* Wf1  = (const float*)d_in[9];
    const float* bf1  = (const float*)d_in[10];
    const float* Wf2  = (const float*)d_in[11];
    const float* bf2  = (const float*)d_in[12];
    float* out = (float*)d_out;

    const int* src = eidx;
    const int* dst = eidx + N_EDGES;

    char* p = (char*)d_ws;
    unsigned short* Xb  = (unsigned short*)p;  p += (size_t)N_NODES * F * 2;
    unsigned short* H1  = (unsigned short*)p;  p += (size_t)N_NODES * F * 2;
    unsigned short* H2  = (unsigned short*)p;  p += (size_t)N_NODES * F * 2;
    unsigned short* H3  = (unsigned short*)p;  p += (size_t)N_NODES * F * 2;
    int2* esw   = (int2*)p;    p += (size_t)N_EDGES * sizeof(int2);
    uint4* Whi  = (uint4*)p;   p += (size_t)3 * 2048 * sizeof(uint4);
    uint4* Wlo  = (uint4*)p;   p += (size_t)3 * 2048 * sizeof(uint4);
    float* dinv = (float*)p;   p += (size_t)N_NODES * sizeof(float);
    int* cnt     = (int*)p;    p += (size_t)N_NODES * sizeof(int);
    int* row_ptr = (int*)p;    p += (size_t)(N_NODES + 1) * sizeof(int);
    int* blksums = (int*)p;    p += 256 * sizeof(int);
    int* gs      = (int*)p;    p += (size_t)(N_GRAPHS + 1) * sizeof(int);

    dim3 b256(256);
    int gNodes = (N_NODES + 255) / 256;           // 196
    int gEdges = (N_EDGES + 255) / 256;
    int gFused = (N_NODES + TN - 1) / TN;         // 3125

    // ---- prep (cvt + hist + prepW + pool bounds merged); cnt must be zero before hist ----
    hipMemsetAsync(cnt, 0, (size_t)N_NODES * sizeof(int), stream);
    k_prep<<<G_CVT + G_HIST + G_PREPW + G_BND, b256, 0, stream>>>(x, Xb, dst, cnt, W1, W2, W3,
                                                                  Whi, Wlo, batch, gs);

    // ---- CSR scan + fill ----
    k_scan1<<<gNodes, b256, 0, stream>>>(cnt, row_ptr, blksums, dinv, N_NODES);
    k_scan23<<<gNodes, b256, 0, stream>>>(row_ptr, blksums, N_NODES, N_EDGES);
    k_fill<<<gEdges, b256, 0, stream>>>(src, dst, row_ptr, cnt, dinv, esw, N_EDGES);

    // ---- 3 aggregate-first fused layers ----
    k_fused<<<gFused, b256, 0, stream>>>(row_ptr, esw, dinv, Xb, Whi,        Wlo,        b1, H1, N_NODES);
    k_fused<<<gFused, b256, 0, stream>>>(row_ptr, esw, dinv, H1, Whi + 2048, Wlo + 2048, b2, H2, N_NODES);
    k_fused<<<gFused, b256, 0, stream>>>(row_ptr, esw, dinv, H2, Whi + 4096, Wlo + 4096, b3, H3, N_NODES);

    // ---- pool + FC ----
    k_pool_fc<<<N_GRAPHS, b256, 0, stream>>>(H3, gs, Wf1, bf1, Wf2, bf2, out);
}